// Round 6
// baseline (402.724 us; speedup 1.0000x reference)
//
#include <hip/hip_runtime.h>
#include <hip/hip_bf16.h>
#include <math.h>

#define Bn 8
#define Sn 1024
#define Dn 768
#define Hn 12
#define MROWS (Bn * Sn)

typedef __attribute__((ext_vector_type(8))) short short8;
typedef __attribute__((ext_vector_type(4))) float floatx4;

__device__ __forceinline__ unsigned short f2b(float x) {
    union { float f; unsigned u; } v; v.f = x;
    unsigned r = v.u + 0x7fffu + ((v.u >> 16) & 1u);
    return (unsigned short)(r >> 16);
}

// pack two floats -> two bf16 (RNE) in one u32 (a = low half)
__device__ __forceinline__ unsigned pk2(float a, float b) {
    union { __hip_bfloat162 h2; unsigned u; } cv;
    cv.h2 = __float22bfloat162_rn(float2{a, b});
    return cv.u;
}

// async 16B global -> LDS (dest = wave-uniform base + lane*16)
__device__ __forceinline__ void gload16(const void* g, void* l) {
    __builtin_amdgcn_global_load_lds(
        (const __attribute__((address_space(1))) void*)g,
        (__attribute__((address_space(3))) void*)l, 16, 0, 0);
}

// Fused fp32->bf16 conversion of X and the 4 weight matrices in one dispatch.
__global__ __launch_bounds__(256) void convert_all(const float* __restrict__ X,
                                                   const float* __restrict__ Wq, const float* __restrict__ Wk,
                                                   const float* __restrict__ Wv, const float* __restrict__ Wo,
                                                   unsigned short* __restrict__ Xb,
                                                   unsigned short* __restrict__ Wqb, unsigned short* __restrict__ Wkb,
                                                   unsigned short* __restrict__ Wvb, unsigned short* __restrict__ Wob) {
    const int id = blockIdx.x;
    const float* src;
    unsigned short* dst;
    int i;
    if (id < 6144) {
        src = X; dst = Xb;
        i = id * 256 + threadIdx.x;
    } else {
        const int y = (id - 6144) / 576;
        src = (y == 0) ? Wq : (y == 1) ? Wk : (y == 2) ? Wv : Wo;
        dst = (y == 0) ? Wqb : (y == 1) ? Wkb : (y == 2) ? Wvb : Wob;
        i = ((id - 6144) % 576) * 256 + threadIdx.x;
    }
    float4 v = reinterpret_cast<const float4*>(src)[i];
    ushort4 o;
    o.x = f2b(v.x); o.y = f2b(v.y); o.z = f2b(v.z); o.w = f2b(v.w);
    reinterpret_cast<ushort4*>(dst)[i] = o;
}

// Fused Q/K/V projection, 128x128 tile, BK=32, double-buffered LDS.
// Q,K: swapped-operand MFMA (C^T) -> per-lane 4 contiguous d -> packed 8B stores.
// V: original order -> per-lane 4 contiguous s in [B,H,64,S] -> packed 8B stores.
__global__ __launch_bounds__(256, 4) void gemm_qkv(const unsigned short* __restrict__ A,
                                                   const unsigned short* __restrict__ Wq,
                                                   const unsigned short* __restrict__ Wk,
                                                   const unsigned short* __restrict__ Wv,
                                                   const float* __restrict__ bq,
                                                   const float* __restrict__ bk,
                                                   const float* __restrict__ bv,
                                                   unsigned short* __restrict__ Qh,
                                                   unsigned short* __restrict__ Kh,
                                                   unsigned short* __restrict__ Vt) {
    __shared__ __align__(16) unsigned short As[2][128 * 32];
    __shared__ __align__(16) unsigned short Ws[2][128 * 32];
    const int id = blockIdx.x;
    const int by = id & 63;
    const int bx = id >> 6;
    const int mat = bx / 6;
    const int m0 = by * 128;
    const int n0 = (bx % 6) * 128;
    const unsigned short* W = (mat == 0) ? Wq : (mat == 1) ? Wk : Wv;
    const float* bias = (mat == 0) ? bq : (mat == 1) ? bk : bv;
    unsigned short* Cout = (mat == 0) ? Qh : (mat == 1) ? Kh : Vt;

    const int tid = threadIdx.x;
    const int w = tid >> 6, l = tid & 63, quad = l >> 4, mr = l & 15;
    const int wm = (w >> 1) * 64, wn = (w & 1) * 64;

    const unsigned short* gA0 = &A[(size_t)(m0 + w * 32 + (l >> 2)) * Dn + (l & 3) * 8];
    const unsigned short* gA1 = gA0 + 16 * Dn;
    const unsigned short* gW0 = &W[(size_t)(n0 + w * 32 + (l >> 2)) * Dn + (l & 3) * 8];
    const unsigned short* gW1 = gW0 + 16 * Dn;
    const int lo = w * 1024;

    floatx4 acc[4][4];
#pragma unroll
    for (int i = 0; i < 4; i++)
#pragma unroll
        for (int j = 0; j < 4; j++) {
            floatx4 z = {0.f, 0.f, 0.f, 0.f};
            acc[i][j] = z;
        }

    gload16(gA0, &As[0][lo]);
    gload16(gA1, &As[0][lo + 512]);
    gload16(gW0, &Ws[0][lo]);
    gload16(gW1, &Ws[0][lo + 512]);

    const bool swapOrd = (mat != 2);
    for (int kt = 0; kt < 24; kt++) {
        const int cur = kt & 1;
        __syncthreads();
        if (kt < 23) {
            const int k0 = (kt + 1) * 32;
            const int nxt = cur ^ 1;
            gload16(gA0 + k0, &As[nxt][lo]);
            gload16(gA1 + k0, &As[nxt][lo + 512]);
            gload16(gW0 + k0, &Ws[nxt][lo]);
            gload16(gW1 + k0, &Ws[nxt][lo + 512]);
        }
        short8 af[4], bfr[4];
#pragma unroll
        for (int i = 0; i < 4; i++)
            af[i] = *(const short8*)&As[cur][(wm + i * 16 + mr) * 32 + quad * 8];
#pragma unroll
        for (int j = 0; j < 4; j++)
            bfr[j] = *(const short8*)&Ws[cur][(wn + j * 16 + mr) * 32 + quad * 8];
        if (swapOrd) {
#pragma unroll
            for (int i = 0; i < 4; i++)
#pragma unroll
                for (int j = 0; j < 4; j++)
                    acc[i][j] = __builtin_amdgcn_mfma_f32_16x16x32_bf16(bfr[j], af[i], acc[i][j], 0, 0, 0);
        } else {
#pragma unroll
            for (int i = 0; i < 4; i++)
#pragma unroll
                for (int j = 0; j < 4; j++)
                    acc[i][j] = __builtin_amdgcn_mfma_f32_16x16x32_bf16(af[i], bfr[j], acc[i][j], 0, 0, 0);
        }
    }

    if (swapOrd) {
        // C^T: rows (quad*4+r) = W-row n (4 contiguous d), cols (mr) = X-row m = s
#pragma unroll
        for (int j = 0; j < 4; j++) {
            const int nb = n0 + wn + j * 16 + quad * 4;
            const float4 b4 = *(const float4*)&bias[nb];
            const int h = nb >> 6, d0 = nb & 63;
#pragma unroll
            for (int i = 0; i < 4; i++) {
                const int m = m0 + wm + i * 16 + mr;
                const int b = m >> 10, s = m & 1023;
                uint2 pp;
                pp.x = pk2(acc[i][j][0] + b4.x, acc[i][j][1] + b4.y);
                pp.y = pk2(acc[i][j][2] + b4.z, acc[i][j][3] + b4.w);
                *(uint2*)&Cout[((size_t)(b * Hn + h) << 16) + (size_t)s * 64 + d0] = pp;
            }
        }
    } else {
        // original: rows (quad*4+r) = s (4 contiguous), cols (mr) = n -> fixed d
#pragma unroll
        for (int j = 0; j < 4; j++) {
            const int col = n0 + wn + j * 16 + mr;
            const float bval = bias[col];
            const int h = col >> 6, d = col & 63;
#pragma unroll
            for (int i = 0; i < 4; i++) {
                const int mb = m0 + wm + i * 16 + quad * 4;
                const int b = mb >> 10, s0 = mb & 1023;
                uint2 pp;
                pp.x = pk2(acc[i][j][0] + bval, acc[i][j][1] + bval);
                pp.y = pk2(acc[i][j][2] + bval, acc[i][j][3] + bval);
                *(uint2*)&Cout[((size_t)(b * Hn + h) << 16) + (size_t)d * 1024 + s0] = pp;
            }
        }
    }
}

// O-projection + residual, swapped-operand MFMA: per-lane 4 contiguous cols ->
// float4 RMW of X/xres. 64x128 tile, 768 blocks, dbuf.
__global__ __launch_bounds__(256, 4) void gemm_out(const unsigned short* __restrict__ A,
                                                   const unsigned short* __restrict__ W,
                                                   const float* __restrict__ bias,
                                                   const float* __restrict__ X,
                                                   float* __restrict__ xres) {
    __shared__ __align__(16) unsigned short As[2][64 * 32];
    __shared__ __align__(16) unsigned short Ws[2][128 * 32];
    const int id = blockIdx.x;
    const int by = id & 127;
    const int bx = id >> 7;
    const int m0 = by * 64;
    const int n0 = bx * 128;

    const int tid = threadIdx.x;
    const int w = tid >> 6, l = tid & 63, quad = l >> 4, mr = l & 15;

    const unsigned short* gA0 = &A[(size_t)(m0 + w * 16 + (l >> 2)) * Dn + (l & 3) * 8];
    const unsigned short* gW0 = &W[(size_t)(n0 + w * 32 + (l >> 2)) * Dn + (l & 3) * 8];
    const unsigned short* gW1 = gW0 + 16 * Dn;
    const int loA = w * 512;
    const int loW = w * 1024;

    floatx4 acc[4][2];
#pragma unroll
    for (int i = 0; i < 4; i++)
#pragma unroll
        for (int j = 0; j < 2; j++) {
            floatx4 z = {0.f, 0.f, 0.f, 0.f};
            acc[i][j] = z;
        }

    gload16(gA0, &As[0][loA]);
    gload16(gW0, &Ws[0][loW]);
    gload16(gW1, &Ws[0][loW + 512]);

    for (int kt = 0; kt < 24; kt++) {
        const int cur = kt & 1;
        __syncthreads();
        if (kt < 23) {
            const int k0 = (kt + 1) * 32;
            const int nxt = cur ^ 1;
            gload16(gA0 + k0, &As[nxt][loA]);
            gload16(gW0 + k0, &Ws[nxt][loW]);
            gload16(gW1 + k0, &Ws[nxt][loW + 512]);
        }
        short8 af[4], bfr[2];
#pragma unroll
        for (int i = 0; i < 4; i++)
            af[i] = *(const short8*)&As[cur][(i * 16 + mr) * 32 + quad * 8];
#pragma unroll
        for (int j = 0; j < 2; j++)
            bfr[j] = *(const short8*)&Ws[cur][(w * 32 + j * 16 + mr) * 32 + quad * 8];
#pragma unroll
        for (int i = 0; i < 4; i++)
#pragma unroll
            for (int j = 0; j < 2; j++)
                acc[i][j] = __builtin_amdgcn_mfma_f32_16x16x32_bf16(bfr[j], af[i], acc[i][j], 0, 0, 0);
    }

#pragma unroll
    for (int j = 0; j < 2; j++) {
        const int nb = n0 + w * 32 + j * 16 + quad * 4;
        const float4 b4 = *(const float4*)&bias[nb];
#pragma unroll
        for (int i = 0; i < 4; i++) {
            const int m = m0 + i * 16 + mr;
            const float4 xr = *(const float4*)&X[(size_t)m * Dn + nb];
            float4 o;
            o.x = acc[i][j][0] + b4.x + xr.x;
            o.y = acc[i][j][1] + b4.y + xr.y;
            o.z = acc[i][j][2] + b4.z + xr.z;
            o.w = acc[i][j][3] + b4.w + xr.w;
            *(float4*)&xres[(size_t)m * Dn + nb] = o;
        }
    }
}

// Flash attention, MFMA, transposed orientation (S^T / O^T), no-max softmax.
// Qh,Kh: [B,H,S,64] bf16; Vt: [B,H,64,S] bf16. ctx: [B,S,768] bf16, head_mask folded.
// Block = 128 q (4 waves x 32q as MFMA columns). P staged as Ps[q][k] -> b64 writes.
__global__ __launch_bounds__(256) void flash_attn_mfma(const unsigned short* __restrict__ Qh,
                                                       const unsigned short* __restrict__ Kh,
                                                       const unsigned short* __restrict__ Vt,
                                                       const float* __restrict__ mask,
                                                       const float* __restrict__ head_mask,
                                                       unsigned short* __restrict__ ctx) {
    __shared__ __align__(16) unsigned short Ks[64 * 72];
    __shared__ __align__(16) unsigned short Vs[64 * 72];
    __shared__ __align__(16) unsigned short Ps[128 * 72];

    const int id = blockIdx.x;
    const int bh = id % 96;
    const int qt = id / 96;
    const int b = bh / Hn, h = bh % Hn;
    const int q0 = qt * 128;
    const int tid = threadIdx.x;
    const int w = tid >> 6, l = tid & 63, quad = l >> 4, mr = l & 15;
    const size_t hb = (size_t)(b * Hn + h) << 16;

    // Q as B-operand fragments (rows q = w*32 + n*16 + mr), held in registers
    short8 bq[2][2];
#pragma unroll
    for (int n = 0; n < 2; n++)
#pragma unroll
        for (int ks = 0; ks < 2; ks++)
            bq[n][ks] = *(const short8*)&Qh[hb + (size_t)(q0 + w * 32 + n * 16 + mr) * 64 + ks * 32 + quad * 8];

    float l_acc[2] = {0.f, 0.f};
    floatx4 oacc[4][2];  // [d-tile][q-tile], O^T layout
#pragma unroll
    for (int dt = 0; dt < 4; dt++)
#pragma unroll
        for (int n = 0; n < 2; n++) {
            floatx4 z = {0.f, 0.f, 0.f, 0.f};
            oacc[dt][n] = z;
        }

    const int srow = tid >> 2;
    const int scol = (tid & 3) * 16;

    // prefetch tile 0
    short8 pk0 = *(const short8*)&Kh[hb + (size_t)srow * 64 + scol];
    short8 pk1 = *(const short8*)&Kh[hb + (size_t)srow * 64 + scol + 8];
    short8 pv0 = *(const short8*)&Vt[hb + (size_t)srow * 1024 + scol];
    short8 pv1 = *(const short8*)&Vt[hb + (size_t)srow * 1024 + scol + 8];
    float4 mm[4];
#pragma unroll
    for (int i = 0; i < 4; i++)
        mm[i] = *(const float4*)&mask[b * Sn + i * 16 + quad * 4];

    for (int kt = 0; kt < Sn / 64; kt++) {
        __syncthreads();  // all waves done reading prev Ks/Vs
        *(short8*)&Ks[srow * 72 + scol] = pk0;
        *(short8*)&Ks[srow * 72 + scol + 8] = pk1;
        *(short8*)&Vs[srow * 72 + scol] = pv0;
        *(short8*)&Vs[srow * 72 + scol + 8] = pv1;
        float4 cm[4];
#pragma unroll
        for (int i = 0; i < 4; i++) cm[i] = mm[i];
        if (kt < Sn / 64 - 1) {
            const int k0 = (kt + 1) * 64;
            pk0 = *(const short8*)&Kh[hb + (size_t)(k0 + srow) * 64 + scol];
            pk1 = *(const short8*)&Kh[hb + (size_t)(k0 + srow) * 64 + scol + 8];
            pv0 = *(const short8*)&Vt[hb + (size_t)srow * 1024 + k0 + scol];
            pv1 = *(const short8*)&Vt[hb + (size_t)srow * 1024 + k0 + scol + 8];
#pragma unroll
            for (int i = 0; i < 4; i++)
                mm[i] = *(const float4*)&mask[b * Sn + k0 + i * 16 + quad * 4];
        }
        __syncthreads();

        // S^T = mfma(K-rows, Q-rows): rows = k (i*16+quad*4+r), cols = q (n*16+mr)
        floatx4 sacc[4][2];
#pragma unroll
        for (int i = 0; i < 4; i++)
#pragma unroll
            for (int n = 0; n < 2; n++) {
                floatx4 z = {0.f, 0.f, 0.f, 0.f};
                sacc[i][n] = z;
            }
#pragma unroll
        for (int ks = 0; ks < 2; ks++) {
#pragma unroll
            for (int i = 0; i < 4; i++) {
                short8 ak = *(const short8*)&Ks[(i * 16 + mr) * 72 + ks * 32 + quad * 8];
                sacc[i][0] = __builtin_amdgcn_mfma_f32_16x16x32_bf16(ak, bq[0][ks], sacc[i][0], 0, 0, 0);
                sacc[i][1] = __builtin_amdgcn_mfma_f32_16x16x32_bf16(ak, bq[1][ks], sacc[i][1], 0, 0, 0);
            }
        }

        // exp (no max: bounded scores), per-lane partial row sums, pack P^T rows to LDS
#pragma unroll
        for (int i = 0; i < 4; i++) {
#pragma unroll
            for (int n = 0; n < 2; n++) {
                const float p0 = __expf(sacc[i][n][0] * 0.125f + cm[i].x);
                const float p1 = __expf(sacc[i][n][1] * 0.125f + cm[i].y);
                const float p2 = __expf(sacc[i][n][2] * 0.125f + cm[i].z);
                const float p3 = __expf(sacc[i][n][3] * 0.125f + cm[i].w);
                l_acc[n] += p0 + p1 + p2 + p3;
                uint2 pp;
                pp.x = pk2(p0, p1);
                pp.y = pk2(p2, p3);
                *(uint2*)&Ps[(w * 32 + n * 16 + mr) * 72 + i * 16 + quad * 4] = pp;
            }
        }
        // wave-private Ps rows: in-wave lgkmcnt orders write->read, no barrier

        // O^T += mfma(V^T-rows(d), P-rows(q))
#pragma unroll
        for (int ks = 0; ks < 2; ks++) {
            short8 bp0 = *(const short8*)&Ps[(w * 32 + mr) * 72 + ks * 32 + quad * 8];
            short8 bp1 = *(const short8*)&Ps[(w * 32 + 16 + mr) * 72 + ks * 32 + quad * 8];
#pragma unroll
            for (int dt = 0; dt < 4; dt++) {
                short8 av = *(const short8*)&Vs[(dt * 16 + mr) * 72 + ks * 32 + quad * 8];
                oacc[dt][0] = __builtin_amdgcn_mfma_f32_16x16x32_bf16(av, bp0, oacc[dt][0], 0, 0, 0);
                oacc[dt][1] = __builtin_amdgcn_mfma_f32_16x16x32_bf16(av, bp1, oacc[dt][1], 0, 0, 0);
            }
        }
    }

    // reduce row sums across quads (lanes mr, mr+16, mr+32, mr+48 share q)
    const float hm = head_mask[h];
    float inv[2];
#pragma unroll
    for (int n = 0; n < 2; n++) {
        float t = l_acc[n];
        t += __shfl_xor(t, 16);
        t += __shfl_xor(t, 32);
        inv[n] = hm / t;
    }
    // ctx write: per lane fixed q, 4 contiguous d per acc -> packed 8B stores
#pragma unroll
    for (int n = 0; n < 2; n++) {
        const int q = q0 + w * 32 + n * 16 + mr;
        unsigned short* dst = &ctx[(size_t)(b * Sn + q) * Dn + h * 64 + quad * 4];
#pragma unroll
        for (int dt = 0; dt < 4; dt++) {
            uint2 pp;
            pp.x = pk2(oacc[dt][n][0] * inv[n], oacc[dt][n][1] * inv[n]);
            pp.y = pk2(oacc[dt][n][2] * inv[n], oacc[dt][n][3] * inv[n]);
            *(uint2*)&dst[dt * 16] = pp;
        }
    }
}

// LayerNorm over xres (residual already added), one block per row of 768
__global__ __launch_bounds__(256) void ln_kernel(const float* __restrict__ x,
                                                 const float* __restrict__ gamma,
                                                 const float* __restrict__ beta,
                                                 float* __restrict__ out) {
    __shared__ float r1[256];
    __shared__ float r2[256];
    const int m = blockIdx.x;
    const int tid = threadIdx.x;

    float xv[3];
    float s = 0.f, ss = 0.f;
#pragma unroll
    for (int i = 0; i < 3; i++) {
        int j = tid + i * 256;
        float t = x[(size_t)m * Dn + j];
        xv[i] = t;
        s += t;
        ss += t * t;
    }
    r1[tid] = s;
    r2[tid] = ss;
    __syncthreads();
    for (int off = 128; off > 0; off >>= 1) {
        if (tid < off) {
            r1[tid] += r1[tid + off];
            r2[tid] += r2[tid + off];
        }
        __syncthreads();
    }
    const float mu = r1[0] * (1.0f / Dn);
    const float var = r2[0] * (1.0f / Dn) - mu * mu;
    const float rstd = rsqrtf(var + 1e-12f);
#pragma unroll
    for (int i = 0; i < 3; i++) {
        int j = tid + i * 256;
        out[(size_t)m * Dn + j] = (xv[i] - mu) * rstd * gamma[j] + beta[j];
    }
}

extern "C" void kernel_launch(void* const* d_in, const int* in_sizes, int n_in,
                              void* d_out, int out_size, void* d_ws, size_t ws_size,
                              hipStream_t stream) {
    const float* X         = (const float*)d_in[0];
    const float* mask      = (const float*)d_in[1];
    const float* head_mask = (const float*)d_in[2];
    const float* Wq        = (const float*)d_in[3];
    const float* bq        = (const float*)d_in[4];
    const float* Wk        = (const float*)d_in[5];
    const float* bk        = (const float*)d_in[6];
    const float* Wv        = (const float*)d_in[7];
    const float* bv        = (const float*)d_in[8];
    const float* Wo        = (const float*)d_in[9];
    const float* bo        = (const float*)d_in[10];
    const float* gamma     = (const float*)d_in[11];
    const float* beta      = (const float*)d_in[12];
    float* out = (float*)d_out;

    const size_t NE = (size_t)Bn * Sn * Dn;   // 6291456
    const size_t NW = (size_t)Dn * Dn;        // 589824

    char* p = (char*)d_ws;
    unsigned short* Xb  = (unsigned short*)p;  p += NE * 2;
    unsigned short* Wqb = (unsigned short*)p;  p += NW * 2;
    unsigned short* Wkb = (unsigned short*)p;  p += NW * 2;
    unsigned short* Wvb = (unsigned short*)p;  p += NW * 2;
    unsigned short* Wob = (unsigned short*)p;  p += NW * 2;
    unsigned short* Qh  = (unsigned short*)p;  p += NE * 2;
    unsigned short* Kh  = (unsigned short*)p;  p += NE * 2;
    unsigned short* Vtb = (unsigned short*)p;  p += NE * 2;
    unsigned short* ctx = (unsigned short*)p;  p += NE * 2;
    float* xres = (float*)p;

    convert_all<<<8448, 256, 0, stream>>>(X, Wq, Wk, Wv, Wo, Xb, Wqb, Wkb, Wvb, Wob);

    gemm_qkv<<<1152, 256, 0, stream>>>(Xb, Wqb, Wkb, Wvb, bq, bk, bv, Qh, Kh, Vtb);

    flash_attn_mfma<<<768, 256, 0, stream>>>(Qh, Kh, Vtb, mask, head_mask, ctx);

    gemm_out<<<768, 256, 0, stream>>>(ctx, Wob, bo, X, xres);

    ln_kernel<<<MROWS, 256, 0, stream>>>(xres, gamma, beta, out);
}

// Round 7
// 340.144 us; speedup vs baseline: 1.1840x; 1.1840x over previous
//
#include <hip/hip_runtime.h>
#include <hip/hip_bf16.h>
#include <math.h>

#define Bn 8
#define Sn 1024
#define Dn 768
#define Hn 12
#define MROWS (Bn * Sn)

typedef __attribute__((ext_vector_type(8))) short short8;
typedef __attribute__((ext_vector_type(4))) float floatx4;

__device__ __forceinline__ unsigned short f2b(float x) {
    union { float f; unsigned u; } v; v.f = x;
    unsigned r = v.u + 0x7fffu + ((v.u >> 16) & 1u);
    return (unsigned short)(r >> 16);
}

// Fused fp32->bf16 conversion of X and the 4 weight matrices in one dispatch.
__global__ __launch_bounds__(256) void convert_all(const float* __restrict__ X,
                                                   const float* __restrict__ Wq, const float* __restrict__ Wk,
                                                   const float* __restrict__ Wv, const float* __restrict__ Wo,
                                                   unsigned short* __restrict__ Xb,
                                                   unsigned short* __restrict__ Wqb, unsigned short* __restrict__ Wkb,
                                                   unsigned short* __restrict__ Wvb, unsigned short* __restrict__ Wob) {
    const int id = blockIdx.x;
    const float* src;
    unsigned short* dst;
    int i;
    if (id < 6144) {
        src = X; dst = Xb;
        i = id * 256 + threadIdx.x;
    } else {
        const int y = (id - 6144) / 576;
        src = (y == 0) ? Wq : (y == 1) ? Wk : (y == 2) ? Wv : Wo;
        dst = (y == 0) ? Wqb : (y == 1) ? Wkb : (y == 2) ? Wvb : Wob;
        i = ((id - 6144) % 576) * 256 + threadIdx.x;
    }
    float4 v = reinterpret_cast<const float4*>(src)[i];
    ushort4 o;
    o.x = f2b(v.x); o.y = f2b(v.y); o.z = f2b(v.z); o.w = f2b(v.w);
    reinterpret_cast<ushort4*>(dst)[i] = o;
}

// Fused Q/K/V projection — barrier-free: MFMA fragments loaded DIRECTLY from
// global (A and W are K-contiguous; a wave's frag load = 16 fully-consumed
// 64B lines, L2-hot). 128x128 tile, 4 waves, manual 1-deep register pipeline.
// Q,K out: [B,H,S,64] bf16; V out: [B,H,64,S] bf16 (transposed).
// Store layout = round-4 scheme (lanes sweep contiguous dim; measured clean).
__global__ __launch_bounds__(256) void gemm_qkv(const unsigned short* __restrict__ A,
                                                const unsigned short* __restrict__ Wq,
                                                const unsigned short* __restrict__ Wk,
                                                const unsigned short* __restrict__ Wv,
                                                const float* __restrict__ bq,
                                                const float* __restrict__ bk,
                                                const float* __restrict__ bv,
                                                unsigned short* __restrict__ Qh,
                                                unsigned short* __restrict__ Kh,
                                                unsigned short* __restrict__ Vt) {
    const int id = blockIdx.x;
    const int by = id & 63;
    const int bx = id >> 6;
    const int mat = bx / 6;
    const int m0 = by * 128;
    const int n0 = (bx % 6) * 128;
    const unsigned short* W = (mat == 0) ? Wq : (mat == 1) ? Wk : Wv;
    const float* bias = (mat == 0) ? bq : (mat == 1) ? bk : bv;
    unsigned short* Cout = (mat == 0) ? Qh : (mat == 1) ? Kh : Vt;

    const int tid = threadIdx.x;
    const int w = tid >> 6, l = tid & 63, quad = l >> 4, mr = l & 15;
    const int wm = (w >> 1) * 64, wn = (w & 1) * 64;

    const unsigned short* pA[4];
    const unsigned short* pW[4];
#pragma unroll
    for (int i = 0; i < 4; i++)
        pA[i] = &A[(size_t)(m0 + wm + i * 16 + mr) * Dn + quad * 8];
#pragma unroll
    for (int j = 0; j < 4; j++)
        pW[j] = &W[(size_t)(n0 + wn + j * 16 + mr) * Dn + quad * 8];

    floatx4 acc[4][4];
#pragma unroll
    for (int i = 0; i < 4; i++)
#pragma unroll
        for (int j = 0; j < 4; j++) {
            floatx4 z = {0.f, 0.f, 0.f, 0.f};
            acc[i][j] = z;
        }

    short8 af[4], bf[4], naf[4], nbf[4];
#pragma unroll
    for (int i = 0; i < 4; i++) af[i] = *(const short8*)pA[i];
#pragma unroll
    for (int j = 0; j < 4; j++) bf[j] = *(const short8*)pW[j];

    for (int kt = 0; kt < 24; kt++) {
        if (kt < 23) {
#pragma unroll
            for (int i = 0; i < 4; i++) naf[i] = *(const short8*)(pA[i] + 32);
#pragma unroll
            for (int j = 0; j < 4; j++) nbf[j] = *(const short8*)(pW[j] + 32);
        }
#pragma unroll
        for (int i = 0; i < 4; i++)
#pragma unroll
            for (int j = 0; j < 4; j++)
                acc[i][j] = __builtin_amdgcn_mfma_f32_16x16x32_bf16(af[i], bf[j], acc[i][j], 0, 0, 0);
#pragma unroll
        for (int i = 0; i < 4; i++) { af[i] = naf[i]; pA[i] += 32; }
#pragma unroll
        for (int j = 0; j < 4; j++) { bf[j] = nbf[j]; pW[j] += 32; }
    }

    // round-4 epilogue (scalar stores; lanes sweep the contiguous dim)
#pragma unroll
    for (int j = 0; j < 4; j++) {
        const int col = n0 + wn + j * 16 + mr;
        const float bval = bias[col];
        const int h = col >> 6, d = col & 63;
#pragma unroll
        for (int i = 0; i < 4; i++) {
#pragma unroll
            for (int r = 0; r < 4; r++) {
                const int m = m0 + wm + i * 16 + quad * 4 + r;
                const float val = acc[i][j][r] + bval;
                const int b = m >> 10, s = m & 1023;
                const size_t base = (size_t)(b * Hn + h) << 16;
                if (mat == 2)
                    Cout[base + (size_t)d * 1024 + s] = f2b(val);
                else
                    Cout[base + (size_t)s * 64 + d] = f2b(val);
            }
        }
    }
}

// O-projection + residual, barrier-free direct-global fragments.
// 64x128 tile (768 blocks), wave w owns cols w*32..+31 over all 64 rows.
__global__ __launch_bounds__(256) void gemm_out(const unsigned short* __restrict__ A,
                                                const unsigned short* __restrict__ W,
                                                const float* __restrict__ bias,
                                                const float* __restrict__ X,
                                                float* __restrict__ xres) {
    const int id = blockIdx.x;
    const int by = id & 127;
    const int bx = id >> 7;
    const int m0 = by * 64;
    const int n0 = bx * 128;

    const int tid = threadIdx.x;
    const int w = tid >> 6, l = tid & 63, quad = l >> 4, mr = l & 15;

    const unsigned short* pA[4];
    const unsigned short* pW[2];
#pragma unroll
    for (int i = 0; i < 4; i++)
        pA[i] = &A[(size_t)(m0 + i * 16 + mr) * Dn + quad * 8];
#pragma unroll
    for (int j = 0; j < 2; j++)
        pW[j] = &W[(size_t)(n0 + w * 32 + j * 16 + mr) * Dn + quad * 8];

    floatx4 acc[4][2];
#pragma unroll
    for (int i = 0; i < 4; i++)
#pragma unroll
        for (int j = 0; j < 2; j++) {
            floatx4 z = {0.f, 0.f, 0.f, 0.f};
            acc[i][j] = z;
        }

    short8 af[4], bf[2], naf[4], nbf[2];
#pragma unroll
    for (int i = 0; i < 4; i++) af[i] = *(const short8*)pA[i];
#pragma unroll
    for (int j = 0; j < 2; j++) bf[j] = *(const short8*)pW[j];

    for (int kt = 0; kt < 24; kt++) {
        if (kt < 23) {
#pragma unroll
            for (int i = 0; i < 4; i++) naf[i] = *(const short8*)(pA[i] + 32);
#pragma unroll
            for (int j = 0; j < 2; j++) nbf[j] = *(const short8*)(pW[j] + 32);
        }
#pragma unroll
        for (int i = 0; i < 4; i++)
#pragma unroll
            for (int j = 0; j < 2; j++)
                acc[i][j] = __builtin_amdgcn_mfma_f32_16x16x32_bf16(af[i], bf[j], acc[i][j], 0, 0, 0);
#pragma unroll
        for (int i = 0; i < 4; i++) { af[i] = naf[i]; pA[i] += 32; }
#pragma unroll
        for (int j = 0; j < 2; j++) { bf[j] = nbf[j]; pW[j] += 32; }
    }

#pragma unroll
    for (int j = 0; j < 2; j++) {
        const int col = n0 + w * 32 + j * 16 + mr;
        const float bval = bias[col];
#pragma unroll
        for (int i = 0; i < 4; i++) {
#pragma unroll
            for (int r = 0; r < 4; r++) {
                const int m = m0 + i * 16 + quad * 4 + r;
                xres[(size_t)m * Dn + col] = acc[i][j][r] + bval + X[(size_t)m * Dn + col];
            }
        }
    }
}

// Flash attention (round-5 version): MFMA, no-max softmax, register-prefetched
// K/V tiles, LDS stride 72. Qh,Kh: [B,H,S,64]; Vt: [B,H,64,S]. ctx: [B,S,768].
__global__ __launch_bounds__(256) void flash_attn_mfma(const unsigned short* __restrict__ Qh,
                                                       const unsigned short* __restrict__ Kh,
                                                       const unsigned short* __restrict__ Vt,
                                                       const float* __restrict__ mask,
                                                       const float* __restrict__ head_mask,
                                                       unsigned short* __restrict__ ctx) {
    __shared__ __align__(16) unsigned short Ks[64 * 72];
    __shared__ __align__(16) unsigned short Vs[64 * 72];
    __shared__ __align__(16) unsigned short Ps[128 * 72];
    __shared__ float msk[64];

    const int id = blockIdx.x;
    const int bh = id % 96;
    const int qt = id / 96;
    const int b = bh / Hn, h = bh % Hn;
    const int q0 = qt * 128;
    const int tid = threadIdx.x;
    const int w = tid >> 6, l = tid & 63, quad = l >> 4, mr = l & 15;
    const size_t hb = (size_t)(b * Hn + h) << 16;

    short8 aq[2][2];
#pragma unroll
    for (int i = 0; i < 2; i++)
#pragma unroll
        for (int ks = 0; ks < 2; ks++)
            aq[i][ks] = *(const short8*)&Qh[hb + (size_t)(q0 + w * 32 + i * 16 + mr) * 64 + ks * 32 + quad * 8];

    float l_s[2][4];
    floatx4 oacc[2][4];
#pragma unroll
    for (int i = 0; i < 2; i++) {
#pragma unroll
        for (int r = 0; r < 4; r++) l_s[i][r] = 0.f;
#pragma unroll
        for (int jj = 0; jj < 4; jj++) {
            floatx4 z = {0.f, 0.f, 0.f, 0.f};
            oacc[i][jj] = z;
        }
    }

    const int srow = tid >> 2;
    const int scol = (tid & 3) * 16;

    short8 pk0 = *(const short8*)&Kh[hb + (size_t)srow * 64 + scol];
    short8 pk1 = *(const short8*)&Kh[hb + (size_t)srow * 64 + scol + 8];
    short8 pv0 = *(const short8*)&Vt[hb + (size_t)srow * 1024 + scol];
    short8 pv1 = *(const short8*)&Vt[hb + (size_t)srow * 1024 + scol + 8];
    float pm = mask[b * Sn + (tid & 63)];

    for (int kt = 0; kt < Sn / 64; kt++) {
        __syncthreads();
        *(short8*)&Ks[srow * 72 + scol] = pk0;
        *(short8*)&Ks[srow * 72 + scol + 8] = pk1;
        *(short8*)&Vs[srow * 72 + scol] = pv0;
        *(short8*)&Vs[srow * 72 + scol + 8] = pv1;
        if (tid < 64) msk[tid] = pm;
        if (kt < Sn / 64 - 1) {
            const int k0 = (kt + 1) * 64;
            pk0 = *(const short8*)&Kh[hb + (size_t)(k0 + srow) * 64 + scol];
            pk1 = *(const short8*)&Kh[hb + (size_t)(k0 + srow) * 64 + scol + 8];
            pv0 = *(const short8*)&Vt[hb + (size_t)srow * 1024 + k0 + scol];
            pv1 = *(const short8*)&Vt[hb + (size_t)srow * 1024 + k0 + scol + 8];
            pm = mask[b * Sn + k0 + (tid & 63)];
        }
        __syncthreads();

        floatx4 sacc[2][4];
#pragma unroll
        for (int i = 0; i < 2; i++)
#pragma unroll
            for (int j = 0; j < 4; j++) {
                floatx4 z = {0.f, 0.f, 0.f, 0.f};
                sacc[i][j] = z;
            }
#pragma unroll
        for (int ks = 0; ks < 2; ks++) {
#pragma unroll
            for (int j = 0; j < 4; j++) {
                short8 bk = *(const short8*)&Ks[(j * 16 + mr) * 72 + ks * 32 + quad * 8];
                sacc[0][j] = __builtin_amdgcn_mfma_f32_16x16x32_bf16(aq[0][ks], bk, sacc[0][j], 0, 0, 0);
                sacc[1][j] = __builtin_amdgcn_mfma_f32_16x16x32_bf16(aq[1][ks], bk, sacc[1][j], 0, 0, 0);
            }
        }

#pragma unroll
        for (int i = 0; i < 2; i++) {
#pragma unroll
            for (int j = 0; j < 4; j++) {
                const float mk = msk[j * 16 + mr];
#pragma unroll
                for (int r = 0; r < 4; r++) {
                    const float p = __expf(sacc[i][j][r] * 0.125f + mk);
                    l_s[i][r] += p;
                    Ps[(w * 32 + i * 16 + quad * 4 + r) * 72 + j * 16 + mr] = f2b(p);
                }
            }
        }

#pragma unroll
        for (int ks = 0; ks < 2; ks++) {
            short8 ap0 = *(const short8*)&Ps[(w * 32 + mr) * 72 + ks * 32 + quad * 8];
            short8 ap1 = *(const short8*)&Ps[(w * 32 + 16 + mr) * 72 + ks * 32 + quad * 8];
#pragma unroll
            for (int jj = 0; jj < 4; jj++) {
                short8 bv = *(const short8*)&Vs[(jj * 16 + mr) * 72 + ks * 32 + quad * 8];
                oacc[0][jj] = __builtin_amdgcn_mfma_f32_16x16x32_bf16(ap0, bv, oacc[0][jj], 0, 0, 0);
                oacc[1][jj] = __builtin_amdgcn_mfma_f32_16x16x32_bf16(ap1, bv, oacc[1][jj], 0, 0, 0);
            }
        }
    }

    const float hm = head_mask[h];
    float inv[2][4];
#pragma unroll
    for (int i = 0; i < 2; i++)
#pragma unroll
        for (int r = 0; r < 4; r++) {
            float t = l_s[i][r];
            t += __shfl_xor(t, 1);
            t += __shfl_xor(t, 2);
            t += __shfl_xor(t, 4);
            t += __shfl_xor(t, 8);
            inv[i][r] = hm / t;
        }
#pragma unroll
    for (int i = 0; i < 2; i++)
#pragma unroll
        for (int jj = 0; jj < 4; jj++)
#pragma unroll
            for (int r = 0; r < 4; r++) {
                const int qrow = q0 + w * 32 + i * 16 + quad * 4 + r;
                ctx[(size_t)(b * Sn + qrow) * Dn + h * 64 + jj * 16 + mr] = f2b(oacc[i][jj][r] * inv[i][r]);
            }
}

// LayerNorm, shuffle-based reduction (1 barrier), one block per row of 768
__global__ __launch_bounds__(256) void ln_kernel(const float* __restrict__ x,
                                                 const float* __restrict__ gamma,
                                                 const float* __restrict__ beta,
                                                 float* __restrict__ out) {
    __shared__ float r1[4];
    __shared__ float r2[4];
    const int m = blockIdx.x;
    const int tid = threadIdx.x;
    const int w = tid >> 6, lane = tid & 63;

    float xv[3];
    float s = 0.f, ss = 0.f;
#pragma unroll
    for (int i = 0; i < 3; i++) {
        int j = tid + i * 256;
        float t = x[(size_t)m * Dn + j];
        xv[i] = t;
        s += t;
        ss += t * t;
    }
#pragma unroll
    for (int o = 1; o < 64; o <<= 1) {
        s += __shfl_xor(s, o);
        ss += __shfl_xor(ss, o);
    }
    if (lane == 0) { r1[w] = s; r2[w] = ss; }
    __syncthreads();
    const float sum = r1[0] + r1[1] + r1[2] + r1[3];
    const float sqs = r2[0] + r2[1] + r2[2] + r2[3];
    const float mu = sum * (1.0f / Dn);
    const float var = sqs * (1.0f / Dn) - mu * mu;
    const float rstd = rsqrtf(var + 1e-12f);
#pragma unroll
    for (int i = 0; i < 3; i++) {
        int j = tid + i * 256;
        out[(size_t)m * Dn + j] = (xv[i] - mu) * rstd * gamma[j] + beta[j];
    }
}

extern "C" void kernel_launch(void* const* d_in, const int* in_sizes, int n_in,
                              void* d_out, int out_size, void* d_ws, size_t ws_size,
                              hipStream_t stream) {
    const float* X         = (const float*)d_in[0];
    const float* mask      = (const float*)d_in[1];
    const float* head_mask = (const float*)d_in[2];
    const float* Wq        = (const float*)d_in[3];
    const float* bq        = (const float*)d_in[4];
    const float* Wk        = (const float*)d_in[5];
    const float* bk        = (const float*)d_in[6];
    const float* Wv        = (const float*)d_in[7];
    const float* bv        = (const float*)d_in[8];
    const float* Wo        = (const float*)d_in[9];
    const float* bo        = (const float*)d_in[10];
    const float* gamma     = (const float*)d_in[11];
    const float* beta      = (const float*)d_in[12];
    float* out = (float*)d_out;

    const size_t NE = (size_t)Bn * Sn * Dn;   // 6291456
    const size_t NW = (size_t)Dn * Dn;        // 589824

    char* p = (char*)d_ws;
    unsigned short* Xb  = (unsigned short*)p;  p += NE * 2;
    unsigned short* Wqb = (unsigned short*)p;  p += NW * 2;
    unsigned short* Wkb = (unsigned short*)p;  p += NW * 2;
    unsigned short* Wvb = (unsigned short*)p;  p += NW * 2;
    unsigned short* Wob = (unsigned short*)p;  p += NW * 2;
    unsigned short* Qh  = (unsigned short*)p;  p += NE * 2;
    unsigned short* Kh  = (unsigned short*)p;  p += NE * 2;
    unsigned short* Vtb = (unsigned short*)p;  p += NE * 2;
    unsigned short* ctx = (unsigned short*)p;  p += NE * 2;
    float* xres = (float*)p;

    convert_all<<<8448, 256, 0, stream>>>(X, Wq, Wk, Wv, Wo, Xb, Wqb, Wkb, Wvb, Wob);

    gemm_qkv<<<1152, 256, 0, stream>>>(Xb, Wqb, Wkb, Wvb, bq, bk, bv, Qh, Kh, Vtb);

    flash_attn_mfma<<<768, 256, 0, stream>>>(Qh, Kh, Vtb, mask, head_mask, ctx);

    gemm_out<<<768, 256, 0, stream>>>(ctx, Wob, bo, X, xres);

    ln_kernel<<<MROWS, 256, 0, stream>>>(xres, gamma, beta, out);
}

// Round 8
// 233.148 us; speedup vs baseline: 1.7273x; 1.4589x over previous
//
#include <hip/hip_runtime.h>
#include <hip/hip_bf16.h>
#include <math.h>

#define Bn 8
#define Sn 1024
#define Dn 768
#define Hn 12
#define MROWS (Bn * Sn)

typedef __attribute__((ext_vector_type(8))) short short8;
typedef __attribute__((ext_vector_type(4))) float floatx4;

__device__ __forceinline__ unsigned short f2b(float x) {
    union { float f; unsigned u; } v; v.f = x;
    unsigned r = v.u + 0x7fffu + ((v.u >> 16) & 1u);
    return (unsigned short)(r >> 16);
}

// async 16B global -> LDS (dest = wave-uniform base + lane*16)
__device__ __forceinline__ void gload16(const void* g, void* l) {
    __builtin_amdgcn_global_load_lds(
        (const __attribute__((address_space(1))) void*)g,
        (__attribute__((address_space(3))) void*)l, 16, 0, 0);
}

// Fused fp32->bf16 conversion of X and the 4 weight matrices in one dispatch.
__global__ __launch_bounds__(256) void convert_all(const float* __restrict__ X,
                                                   const float* __restrict__ Wq, const float* __restrict__ Wk,
                                                   const float* __restrict__ Wv, const float* __restrict__ Wo,
                                                   unsigned short* __restrict__ Xb,
                                                   unsigned short* __restrict__ Wqb, unsigned short* __restrict__ Wkb,
                                                   unsigned short* __restrict__ Wvb, unsigned short* __restrict__ Wob) {
    const int id = blockIdx.x;
    const float* src;
    unsigned short* dst;
    int i;
    if (id < 6144) {
        src = X; dst = Xb;
        i = id * 256 + threadIdx.x;
    } else {
        const int y = (id - 6144) / 576;
        src = (y == 0) ? Wq : (y == 1) ? Wk : (y == 2) ? Wv : Wo;
        dst = (y == 0) ? Wqb : (y == 1) ? Wkb : (y == 2) ? Wvb : Wob;
        i = ((id - 6144) % 576) * 256 + threadIdx.x;
    }
    float4 v = reinterpret_cast<const float4*>(src)[i];
    ushort4 o;
    o.x = f2b(v.x); o.y = f2b(v.y); o.z = f2b(v.z); o.w = f2b(v.w);
    reinterpret_cast<ushort4*>(dst)[i] = o;
}

// Fused Q/K/V projection. 128x128 tile, BK=64 (12 iters), single-buffer LDS
// staged via global_load_lds with XOR-swizzled layout:
//   16B unit (row, c) lives at LDS unit row*8 + (c ^ (row&7))
// -> fragment ds_read_b128 hits every 4-bank group exactly 2x (free),
//    and all fragment addresses are loop-invariant.
// Q,K out: [B,H,S,64] bf16; V out: [B,H,64,S] bf16 (transposed).
__global__ __launch_bounds__(256) void gemm_qkv(const unsigned short* __restrict__ A,
                                                const unsigned short* __restrict__ Wq,
                                                const unsigned short* __restrict__ Wk,
                                                const unsigned short* __restrict__ Wv,
                                                const float* __restrict__ bq,
                                                const float* __restrict__ bk,
                                                const float* __restrict__ bv,
                                                unsigned short* __restrict__ Qh,
                                                unsigned short* __restrict__ Kh,
                                                unsigned short* __restrict__ Vt) {
    __shared__ __align__(16) unsigned short As[128 * 64];
    __shared__ __align__(16) unsigned short Ws[128 * 64];
    const int id = blockIdx.x;
    const int by = id & 63;
    const int bx = id >> 6;
    const int mat = bx / 6;
    const int m0 = by * 128;
    const int n0 = (bx % 6) * 128;
    const unsigned short* W = (mat == 0) ? Wq : (mat == 1) ? Wk : Wv;
    const float* bias = (mat == 0) ? bq : (mat == 1) ? bk : bv;
    unsigned short* Cout = (mat == 0) ? Qh : (mat == 1) ? Kh : Vt;

    const int tid = threadIdx.x;
    const int w = tid >> 6, l = tid & 63, quad = l >> 4, mr = l & 15;
    const int wm = (w >> 1) * 64, wn = (w & 1) * 64;

    // staging: thread tid handles units {tid + j*256}, j<4 (1024 units each mat)
    const unsigned short* gAsrc[4];
    const unsigned short* gWsrc[4];
    unsigned short* lAdst[4];
    unsigned short* lWdst[4];
#pragma unroll
    for (int j = 0; j < 4; j++) {
        const int u = tid + j * 256;
        const int r = u >> 3, c = u & 7;
        const int kq = (c ^ (r & 7)) * 8;
        gAsrc[j] = &A[(size_t)(m0 + r) * Dn + kq];
        gWsrc[j] = &W[(size_t)(n0 + r) * Dn + kq];
        lAdst[j] = &As[u * 8];
        lWdst[j] = &Ws[u * 8];
    }

    // loop-invariant fragment LDS offsets (elems)
    int aoff[4][2], woff[4][2];
#pragma unroll
    for (int i = 0; i < 4; i++) {
        const int ra = wm + i * 16 + mr;
        const int rw = wn + i * 16 + mr;
#pragma unroll
        for (int ks = 0; ks < 2; ks++) {
            aoff[i][ks] = (ra * 8 + ((quad + ks * 4) ^ (ra & 7))) * 8;
            woff[i][ks] = (rw * 8 + ((quad + ks * 4) ^ (rw & 7))) * 8;
        }
    }

    floatx4 acc[4][4];
#pragma unroll
    for (int i = 0; i < 4; i++)
#pragma unroll
        for (int j = 0; j < 4; j++) {
            floatx4 z = {0.f, 0.f, 0.f, 0.f};
            acc[i][j] = z;
        }

    for (int kt = 0; kt < 12; kt++) {
        const int k0 = kt * 64;
        __syncthreads();  // prev iter reads done
#pragma unroll
        for (int j = 0; j < 4; j++) {
            gload16(gAsrc[j] + k0, lAdst[j]);
            gload16(gWsrc[j] + k0, lWdst[j]);
        }
        __syncthreads();  // staged data visible

        short8 af[4][2], bf[4][2];
#pragma unroll
        for (int i = 0; i < 4; i++)
#pragma unroll
            for (int ks = 0; ks < 2; ks++) {
                af[i][ks] = *(const short8*)&As[aoff[i][ks]];
                bf[i][ks] = *(const short8*)&Ws[woff[i][ks]];
            }
#pragma unroll
        for (int ks = 0; ks < 2; ks++)
#pragma unroll
            for (int i = 0; i < 4; i++)
#pragma unroll
                for (int j = 0; j < 4; j++)
                    acc[i][j] = __builtin_amdgcn_mfma_f32_16x16x32_bf16(af[i][ks], bf[j][ks], acc[i][j], 0, 0, 0);
    }

    // round-4 epilogue (scalar stores; lanes sweep the contiguous dim — measured clean)
#pragma unroll
    for (int j = 0; j < 4; j++) {
        const int col = n0 + wn + j * 16 + mr;
        const float bval = bias[col];
        const int h = col >> 6, d = col & 63;
#pragma unroll
        for (int i = 0; i < 4; i++) {
#pragma unroll
            for (int r = 0; r < 4; r++) {
                const int m = m0 + wm + i * 16 + quad * 4 + r;
                const float val = acc[i][j][r] + bval;
                const int b = m >> 10, s = m & 1023;
                const size_t base = (size_t)(b * Hn + h) << 16;
                if (mat == 2)
                    Cout[base + (size_t)d * 1024 + s] = f2b(val);
                else
                    Cout[base + (size_t)s * 64 + d] = f2b(val);
            }
        }
    }
}

// O-projection + residual: xres = ctx @ Wo^T + bo + X (fp32 out).
// 64x128 tile (768 blocks), BK=64, single-buffer swizzled staging.
__global__ __launch_bounds__(256) void gemm_out(const unsigned short* __restrict__ A,
                                                const unsigned short* __restrict__ W,
                                                const float* __restrict__ bias,
                                                const float* __restrict__ X,
                                                float* __restrict__ xres) {
    __shared__ __align__(16) unsigned short As[64 * 64];
    __shared__ __align__(16) unsigned short Ws[128 * 64];
    const int id = blockIdx.x;
    const int by = id & 127;
    const int bx = id >> 7;
    const int m0 = by * 64;
    const int n0 = bx * 128;

    const int tid = threadIdx.x;
    const int w = tid >> 6, l = tid & 63, quad = l >> 4, mr = l & 15;

    const unsigned short* gAsrc[2];
    unsigned short* lAdst[2];
#pragma unroll
    for (int j = 0; j < 2; j++) {
        const int u = tid + j * 256;  // 512 A units
        const int r = u >> 3, c = u & 7;
        gAsrc[j] = &A[(size_t)(m0 + r) * Dn + (c ^ (r & 7)) * 8];
        lAdst[j] = &As[u * 8];
    }
    const unsigned short* gWsrc[4];
    unsigned short* lWdst[4];
#pragma unroll
    for (int j = 0; j < 4; j++) {
        const int u = tid + j * 256;  // 1024 W units
        const int r = u >> 3, c = u & 7;
        gWsrc[j] = &W[(size_t)(n0 + r) * Dn + (c ^ (r & 7)) * 8];
        lWdst[j] = &Ws[u * 8];
    }

    int aoff[4][2], woff[2][2];
#pragma unroll
    for (int i = 0; i < 4; i++) {
        const int ra = i * 16 + mr;
#pragma unroll
        for (int ks = 0; ks < 2; ks++)
            aoff[i][ks] = (ra * 8 + ((quad + ks * 4) ^ (ra & 7))) * 8;
    }
#pragma unroll
    for (int j = 0; j < 2; j++) {
        const int rw = w * 32 + j * 16 + mr;
#pragma unroll
        for (int ks = 0; ks < 2; ks++)
            woff[j][ks] = (rw * 8 + ((quad + ks * 4) ^ (rw & 7))) * 8;
    }

    floatx4 acc[4][2];
#pragma unroll
    for (int i = 0; i < 4; i++)
#pragma unroll
        for (int j = 0; j < 2; j++) {
            floatx4 z = {0.f, 0.f, 0.f, 0.f};
            acc[i][j] = z;
        }

    for (int kt = 0; kt < 12; kt++) {
        const int k0 = kt * 64;
        __syncthreads();
#pragma unroll
        for (int j = 0; j < 2; j++) gload16(gAsrc[j] + k0, lAdst[j]);
#pragma unroll
        for (int j = 0; j < 4; j++) gload16(gWsrc[j] + k0, lWdst[j]);
        __syncthreads();

        short8 af[4][2], bf[2][2];
#pragma unroll
        for (int i = 0; i < 4; i++)
#pragma unroll
            for (int ks = 0; ks < 2; ks++)
                af[i][ks] = *(const short8*)&As[aoff[i][ks]];
#pragma unroll
        for (int j = 0; j < 2; j++)
#pragma unroll
            for (int ks = 0; ks < 2; ks++)
                bf[j][ks] = *(const short8*)&Ws[woff[j][ks]];
#pragma unroll
        for (int ks = 0; ks < 2; ks++)
#pragma unroll
            for (int i = 0; i < 4; i++)
#pragma unroll
                for (int j = 0; j < 2; j++)
                    acc[i][j] = __builtin_amdgcn_mfma_f32_16x16x32_bf16(af[i][ks], bf[j][ks], acc[i][j], 0, 0, 0);
    }

#pragma unroll
    for (int j = 0; j < 2; j++) {
        const int col = n0 + w * 32 + j * 16 + mr;
        const float bval = bias[col];
#pragma unroll
        for (int i = 0; i < 4; i++) {
#pragma unroll
            for (int r = 0; r < 4; r++) {
                const int m = m0 + i * 16 + quad * 4 + r;
                xres[(size_t)m * Dn + col] = acc[i][j][r] + bval + X[(size_t)m * Dn + col];
            }
        }
    }
}

// Flash attention (round-5 version, measured good): MFMA, no-max softmax,
// register-prefetched K/V tiles, LDS stride 72.
__global__ __launch_bounds__(256) void flash_attn_mfma(const unsigned short* __restrict__ Qh,
                                                       const unsigned short* __restrict__ Kh,
                                                       const unsigned short* __restrict__ Vt,
                                                       const float* __restrict__ mask,
                                                       const float* __restrict__ head_mask,
                                                       unsigned short* __restrict__ ctx) {
    __shared__ __align__(16) unsigned short Ks[64 * 72];
    __shared__ __align__(16) unsigned short Vs[64 * 72];
    __shared__ __align__(16) unsigned short Ps[128 * 72];
    __shared__ float msk[64];

    const int id = blockIdx.x;
    const int bh = id % 96;
    const int qt = id / 96;
    const int b = bh / Hn, h = bh % Hn;
    const int q0 = qt * 128;
    const int tid = threadIdx.x;
    const int w = tid >> 6, l = tid & 63, quad = l >> 4, mr = l & 15;
    const size_t hb = (size_t)(b * Hn + h) << 16;

    short8 aq[2][2];
#pragma unroll
    for (int i = 0; i < 2; i++)
#pragma unroll
        for (int ks = 0; ks < 2; ks++)
            aq[i][ks] = *(const short8*)&Qh[hb + (size_t)(q0 + w * 32 + i * 16 + mr) * 64 + ks * 32 + quad * 8];

    float l_s[2][4];
    floatx4 oacc[2][4];
#pragma unroll
    for (int i = 0; i < 2; i++) {
#pragma unroll
        for (int r = 0; r < 4; r++) l_s[i][r] = 0.f;
#pragma unroll
        for (int jj = 0; jj < 4; jj++) {
            floatx4 z = {0.f, 0.f, 0.f, 0.f};
            oacc[i][jj] = z;
        }
    }

    const int srow = tid >> 2;
    const int scol = (tid & 3) * 16;

    short8 pk0 = *(const short8*)&Kh[hb + (size_t)srow * 64 + scol];
    short8 pk1 = *(const short8*)&Kh[hb + (size_t)srow * 64 + scol + 8];
    short8 pv0 = *(const short8*)&Vt[hb + (size_t)srow * 1024 + scol];
    short8 pv1 = *(const short8*)&Vt[hb + (size_t)srow * 1024 + scol + 8];
    float pm = mask[b * Sn + (tid & 63)];

    for (int kt = 0; kt < Sn / 64; kt++) {
        __syncthreads();
        *(short8*)&Ks[srow * 72 + scol] = pk0;
        *(short8*)&Ks[srow * 72 + scol + 8] = pk1;
        *(short8*)&Vs[srow * 72 + scol] = pv0;
        *(short8*)&Vs[srow * 72 + scol + 8] = pv1;
        if (tid < 64) msk[tid] = pm;
        if (kt < Sn / 64 - 1) {
            const int k0 = (kt + 1) * 64;
            pk0 = *(const short8*)&Kh[hb + (size_t)(k0 + srow) * 64 + scol];
            pk1 = *(const short8*)&Kh[hb + (size_t)(k0 + srow) * 64 + scol + 8];
            pv0 = *(const short8*)&Vt[hb + (size_t)srow * 1024 + k0 + scol];
            pv1 = *(const short8*)&Vt[hb + (size_t)srow * 1024 + k0 + scol + 8];
            pm = mask[b * Sn + k0 + (tid & 63)];
        }
        __syncthreads();

        floatx4 sacc[2][4];
#pragma unroll
        for (int i = 0; i < 2; i++)
#pragma unroll
            for (int j = 0; j < 4; j++) {
                floatx4 z = {0.f, 0.f, 0.f, 0.f};
                sacc[i][j] = z;
            }
#pragma unroll
        for (int ks = 0; ks < 2; ks++) {
#pragma unroll
            for (int j = 0; j < 4; j++) {
                short8 bk = *(const short8*)&Ks[(j * 16 + mr) * 72 + ks * 32 + quad * 8];
                sacc[0][j] = __builtin_amdgcn_mfma_f32_16x16x32_bf16(aq[0][ks], bk, sacc[0][j], 0, 0, 0);
                sacc[1][j] = __builtin_amdgcn_mfma_f32_16x16x32_bf16(aq[1][ks], bk, sacc[1][j], 0, 0, 0);
            }
        }

#pragma unroll
        for (int i = 0; i < 2; i++) {
#pragma unroll
            for (int j = 0; j < 4; j++) {
                const float mk = msk[j * 16 + mr];
#pragma unroll
                for (int r = 0; r < 4; r++) {
                    const float p = __expf(sacc[i][j][r] * 0.125f + mk);
                    l_s[i][r] += p;
                    Ps[(w * 32 + i * 16 + quad * 4 + r) * 72 + j * 16 + mr] = f2b(p);
                }
            }
        }

#pragma unroll
        for (int ks = 0; ks < 2; ks++) {
            short8 ap0 = *(const short8*)&Ps[(w * 32 + mr) * 72 + ks * 32 + quad * 8];
            short8 ap1 = *(const short8*)&Ps[(w * 32 + 16 + mr) * 72 + ks * 32 + quad * 8];
#pragma unroll
            for (int jj = 0; jj < 4; jj++) {
                short8 bv = *(const short8*)&Vs[(jj * 16 + mr) * 72 + ks * 32 + quad * 8];
                oacc[0][jj] = __builtin_amdgcn_mfma_f32_16x16x32_bf16(ap0, bv, oacc[0][jj], 0, 0, 0);
                oacc[1][jj] = __builtin_amdgcn_mfma_f32_16x16x32_bf16(ap1, bv, oacc[1][jj], 0, 0, 0);
            }
        }
    }

    const float hm = head_mask[h];
    float inv[2][4];
#pragma unroll
    for (int i = 0; i < 2; i++)
#pragma unroll
        for (int r = 0; r < 4; r++) {
            float t = l_s[i][r];
            t += __shfl_xor(t, 1);
            t += __shfl_xor(t, 2);
            t += __shfl_xor(t, 4);
            t += __shfl_xor(t, 8);
            inv[i][r] = hm / t;
        }
#pragma unroll
    for (int i = 0; i < 2; i++)
#pragma unroll
        for (int jj = 0; jj < 4; jj++)
#pragma unroll
            for (int r = 0; r < 4; r++) {
                const int qrow = q0 + w * 32 + i * 16 + quad * 4 + r;
                ctx[(size_t)(b * Sn + qrow) * Dn + h * 64 + jj * 16 + mr] = f2b(oacc[i][jj][r] * inv[i][r]);
            }
}

// LayerNorm, shuffle-based reduction (1 barrier), one block per row of 768
__global__ __launch_bounds__(256) void ln_kernel(const float* __restrict__ x,
                                                 const float* __restrict__ gamma,
                                                 const float* __restrict__ beta,
                                                 float* __restrict__ out) {
    __shared__ float r1[4];
    __shared__ float r2[4];
    const int m = blockIdx.x;
    const int tid = threadIdx.x;
    const int w = tid >> 6, lane = tid & 63;

    float xv[3];
    float s = 0.f, ss = 0.f;
#pragma unroll
    for (int i = 0; i < 3; i++) {
        int j = tid + i * 256;
        float t = x[(size_t)m * Dn + j];
        xv[i] = t;
        s += t;
        ss += t * t;
    }
#pragma unroll
    for (int o = 1; o < 64; o <<= 1) {
        s += __shfl_xor(s, o);
        ss += __shfl_xor(ss, o);
    }
    if (lane == 0) { r1[w] = s; r2[w] = ss; }
    __syncthreads();
    const float sum = r1[0] + r1[1] + r1[2] + r1[3];
    const float sqs = r2[0] + r2[1] + r2[2] + r2[3];
    const float mu = sum * (1.0f / Dn);
    const float var = sqs * (1.0f / Dn) - mu * mu;
    const float rstd = rsqrtf(var + 1e-12f);
#pragma unroll
    for (int i = 0; i < 3; i++) {
        int j = tid + i * 256;
        out[(size_t)m * Dn + j] = (xv[i] - mu) * rstd * gamma[j] + beta[j];
    }
}

extern "C" void kernel_launch(void* const* d_in, const int* in_sizes, int n_in,
                              void* d_out, int out_size, void* d_ws, size_t ws_size,
                              hipStream_t stream) {
    const float* X         = (const float*)d_in[0];
    const float* mask      = (const float*)d_in[1];
    const float* head_mask = (const float*)d_in[2];
    const float* Wq        = (const float*)d_in[3];
    const float* bq        = (const float*)d_in[4];
    const float* Wk        = (const float*)d_in[5];
    const float* bk        = (const float*)d_in[6];
    const float* Wv        = (const float*)d_in[7];
    const float* bv        = (const float*)d_in[8];
    const float* Wo        = (const float*)d_in[9];
    const float* bo        = (const float*)d_in[10];
    const float* gamma     = (const float*)d_in[11];
    const float* beta      = (const float*)d_in[12];
    float* out = (float*)d_out;

    const size_t NE = (size_t)Bn * Sn * Dn;   // 6291456
    const size_t NW = (size_t)Dn * Dn;        // 589824

    char* p = (char*)d_ws;
    unsigned short* Xb  = (unsigned short*)p;  p += NE * 2;
    unsigned short* Wqb = (unsigned short*)p;  p += NW * 2;
    unsigned short* Wkb = (unsigned short*)p;  p += NW * 2;
    unsigned short* Wvb = (unsigned short*)p;  p += NW * 2;
    unsigned short* Wob = (unsigned short*)p;  p += NW * 2;
    unsigned short* Qh  = (unsigned short*)p;  p += NE * 2;
    unsigned short* Kh  = (unsigned short*)p;  p += NE * 2;
    unsigned short* Vtb = (unsigned short*)p;  p += NE * 2;
    unsigned short* ctx = (unsigned short*)p;  p += NE * 2;
    float* xres = (float*)p;

    convert_all<<<8448, 256, 0, stream>>>(X, Wq, Wk, Wv, Wo, Xb, Wqb, Wkb, Wvb, Wob);

    gemm_qkv<<<1152, 256, 0, stream>>>(Xb, Wqb, Wkb, Wvb, bq, bk, bv, Qh, Kh, Vtb);

    flash_attn_mfma<<<768, 256, 0, stream>>>(Qh, Kh, Vtb, mask, head_mask, ctx);

    gemm_out<<<768, 256, 0, stream>>>(ctx, Wob, bo, X, xres);

    ln_kernel<<<MROWS, 256, 0, stream>>>(xres, gamma, beta, out);
}